// Round 6
// baseline (128.165 us; speedup 1.0000x reference)
//
#include <hip/hip_runtime.h>
#include <hip/hip_bf16.h>

typedef __bf16 v8bf16 __attribute__((ext_vector_type(8)));
typedef float  v4f32  __attribute__((ext_vector_type(4)));

#define MAIN_GRID 1024

static __device__ __forceinline__ float silu_f(float v) {
    return v / (1.0f + __expf(-v));
}

static __device__ __forceinline__ v8bf16 cvt8(v4f32 f0, v4f32 f1) {
    v8bf16 t;
    t[0] = (__bf16)f0[0]; t[1] = (__bf16)f0[1]; t[2] = (__bf16)f0[2]; t[3] = (__bf16)f0[3];
    t[4] = (__bf16)f1[0]; t[5] = (__bf16)f1[1]; t[6] = (__bf16)f1[2]; t[7] = (__bf16)f1[3];
    return t;
}

__global__ void zero_ws_kernel(float* __restrict__ ws, int n) {
    int i = blockIdx.x * blockDim.x + threadIdx.x;
    if (i < n) ws[i] = 0.0f;
}

// Register-staged, barrier-free, per-wave-independent pipeline.
// Per 64-atom chunk each wave owns 16 rows; lane l needs exactly
// x[row][kt*32 + lg*8 .. +7] for kt=0..3 (its MFMA A-fragment slices) --
// loaded straight into VGPRs via 8 x dwordx4, no LDS, no swizzle, no
// barriers. Depth-1 software pipeline: consume staged regs (cvt->bf16)
// FIRST, then reissue loads for the next chunk into the same regs; the
// compiler's exact vmcnt tracking retires only ops issued a full
// iteration earlier. Metadata (pos/batch/z) prefetched one chunk ahead;
// atomic-mass table in LDS so the epilogue's dependent gather rides
// lgkmcnt, never vmcnt (a vmcnt wait there would drain the prefetch).
__launch_bounds__(256)
__global__ void mlp_dipole_kernel(
    const float* __restrict__ x, const float* __restrict__ pos,
    const float* __restrict__ W1, const float* __restrict__ b1,
    const float* __restrict__ W2, const float* __restrict__ b2,
    const float* __restrict__ am, const int* __restrict__ z,
    const int* __restrict__ batch, float* __restrict__ ws,
    int N, int nChunks, int amN)
{
    __shared__ float amt[128];        // atomic-mass table

    const int tid  = threadIdx.x;
    const int lane = tid & 63;
    const int w    = tid >> 6;        // wave 0..3
    const int l15  = lane & 15;
    const int lg   = lane >> 4;

    if (tid < amN) amt[tid] = am[tid];

    float b1v[4], w2v[4];
#pragma unroll
    for (int ct = 0; ct < 4; ++ct) {
        b1v[ct] = b1[ct * 16 + l15];
        w2v[ct] = W2[ct * 16 + l15];
    }
    const float b2s = b2[0];

    // W1 fragments, register-resident for the whole kernel
    v8bf16 bf[4][4];
#pragma unroll
    for (int kt = 0; kt < 4; ++kt) {
#pragma unroll
        for (int ct = 0; ct < 4; ++ct) {
            const float* src = W1 + (ct * 16 + l15) * 128 + kt * 32 + lg * 8;
            v4f32 f0 = *reinterpret_cast<const v4f32*>(src);
            v4f32 f1 = *reinterpret_cast<const v4f32*>(src + 4);
            bf[kt][ct] = cvt8(f0, f1);
        }
    }

    __syncthreads();   // amt visible to all waves (only barrier in the kernel)

    long ch = blockIdx.x;
    const long gstride = gridDim.x;

    // ---- prologue: stage chunk0 into regs + gather chunk0 metadata ----
    v4f32 st[8];
#pragma unroll
    for (int i = 0; i < 8; ++i) st[i] = (v4f32){0.f, 0.f, 0.f, 0.f};

    if (ch < nChunks) {
        int arow = (int)(ch * 64) + w * 16 + l15;
        if (arow >= N) arow = N - 1;
        const float* xrow = x + (long)arow * 128 + lg * 8;
#pragma unroll
        for (int kt = 0; kt < 4; ++kt) {
            st[2 * kt]     = *reinterpret_cast<const v4f32*>(xrow + kt * 32);
            st[2 * kt + 1] = *reinterpret_cast<const v4f32*>(xrow + kt * 32 + 4);
        }
    }

    float gpx = 0.f, gpy = 0.f, gpz = 0.f;
    int gbi = 0, gzi = 0;
    if (lane < 16 && ch < nChunks) {
        int a = (int)(ch * 64) + w * 16 + lane;
        int ac = (a < N) ? a : N - 1;
        gpx = pos[ac * 3 + 0]; gpy = pos[ac * 3 + 1]; gpz = pos[ac * 3 + 2];
        gbi = batch[ac]; gzi = z[ac];
    }

    while (ch < nChunks) {
        const long nxt = ch + gstride;
        const bool hasNxt = (nxt < nChunks);

        // 1. consume staged regs -> bf16 A-fragments (waits only on loads
        //    issued a full iteration ago; in-order retirement never touches
        //    anything younger)
        v8bf16 af[4];
#pragma unroll
        for (int kt = 0; kt < 4; ++kt)
            af[kt] = cvt8(st[2 * kt], st[2 * kt + 1]);

        // 2. reissue staging loads for the next chunk (st regs now free)
        if (hasNxt) {
            int arow = (int)(nxt * 64) + w * 16 + l15;
            if (arow >= N) arow = N - 1;
            const float* xrow = x + (long)arow * 128 + lg * 8;
#pragma unroll
            for (int kt = 0; kt < 4; ++kt) {
                st[2 * kt]     = *reinterpret_cast<const v4f32*>(xrow + kt * 32);
                st[2 * kt + 1] = *reinterpret_cast<const v4f32*>(xrow + kt * 32 + 4);
            }
        }

        // 3. MFMA: acc[ct] += A(16x32) * W1(32x16) over 4 k-tiles
        v4f32 acc[4];
#pragma unroll
        for (int ct = 0; ct < 4; ++ct) acc[ct] = (v4f32){0.f, 0.f, 0.f, 0.f};
#pragma unroll
        for (int kt = 0; kt < 4; ++kt) {
#pragma unroll
            for (int ct = 0; ct < 4; ++ct)
                acc[ct] = __builtin_amdgcn_mfma_f32_16x16x32_bf16(af[kt], bf[kt][ct], acc[ct], 0, 0, 0);
        }

        // 4. prefetch NEXT chunk's metadata
        float npx = 0.f, npy = 0.f, npz = 0.f;
        int nbi = 0, nzi = 0;
        if (lane < 16 && hasNxt) {
            int a = (int)(nxt * 64) + w * 16 + lane;
            int ac = (a < N) ? a : N - 1;
            npx = pos[ac * 3 + 0]; npy = pos[ac * 3 + 1]; npz = pos[ac * 3 + 2];
            nbi = batch[ac]; nzi = z[ac];
        }

        // 5. xo = silu(acc+b1).w2 reduced over the 64 channels
        float part0 = 0.f, part1 = 0.f, part2 = 0.f, part3 = 0.f;
#pragma unroll
        for (int ct = 0; ct < 4; ++ct) {
            part0 += silu_f(acc[ct][0] + b1v[ct]) * w2v[ct];
            part1 += silu_f(acc[ct][1] + b1v[ct]) * w2v[ct];
            part2 += silu_f(acc[ct][2] + b1v[ct]) * w2v[ct];
            part3 += silu_f(acc[ct][3] + b1v[ct]) * w2v[ct];
        }
#pragma unroll
        for (int d = 1; d < 16; d <<= 1) {
            part0 += __shfl_xor(part0, d);
            part1 += __shfl_xor(part1, d);
            part2 += __shfl_xor(part2, d);
            part3 += __shfl_xor(part3, d);
        }
        const int srcl = (l15 >> 2) << 4;
        float t0 = __shfl(part0, srcl);
        float t1 = __shfl(part1, srcl);
        float t2 = __shfl(part2, srcl);
        float t3 = __shfl(part3, srcl);
        const int rr = lane & 3;
        float xo = ((rr == 0) ? t0 : (rr == 1) ? t1 : (rr == 2) ? t2 : t3) + b2s;

        // 6. dipole accumulation for this wave's 16 atoms (regs + LDS only)
        if (lane < 16) {
            int a = (int)(ch * 64) + w * 16 + lane;
            bool valid = (a < N);
            float sc = valid ? 1.0f : 0.0f;
            float px = gpx, py = gpy, pz = gpz;
            int   bi = gbi;
            float m  = amt[gzi];
            float v0 = sc * xo * px, v1 = sc * xo * py, v2 = sc * xo * pz, v3 = sc * xo;
            float v4 = sc * m  * px, v5 = sc * m  * py, v6 = sc * m  * pz, v7 = sc * m;

            int bprev = __shfl_up(bi, 1);
            bool head = (lane == 0) || (bi != bprev);
            unsigned long long hm = __ballot(head);
            unsigned long long below = hm & ((2ull << lane) - 1ull);
            int rs = 63 - __builtin_clzll(below);

#define SCAN_STEP(d)                                                            \
            {                                                                   \
                float u0 = __shfl_up(v0, d), u1 = __shfl_up(v1, d);             \
                float u2 = __shfl_up(v2, d), u3 = __shfl_up(v3, d);             \
                float u4 = __shfl_up(v4, d), u5 = __shfl_up(v5, d);             \
                float u6 = __shfl_up(v6, d), u7 = __shfl_up(v7, d);             \
                if (lane >= rs + d) {                                           \
                    v0 += u0; v1 += u1; v2 += u2; v3 += u3;                     \
                    v4 += u4; v5 += u5; v6 += u6; v7 += u7;                     \
                }                                                               \
            }
            SCAN_STEP(1)
            SCAN_STEP(2)
            SCAN_STEP(4)
            SCAN_STEP(8)
#undef SCAN_STEP

            bool tail = (lane == 15) || ((hm >> (lane + 1)) & 1ull);
            if (tail) {
                float* p = ws + (long)bi * 8;
                atomicAdd(p + 0, v0);
                atomicAdd(p + 1, v1);
                atomicAdd(p + 2, v2);
                atomicAdd(p + 3, v3);
                atomicAdd(p + 4, v4);
                atomicAdd(p + 5, v5);
                atomicAdd(p + 6, v6);
                atomicAdd(p + 7, v7);
            }
        }

        gpx = npx; gpy = npy; gpz = npz; gbi = nbi; gzi = nzi;
        ch = nxt;
    }
}

__global__ void finalize_kernel(const float* __restrict__ ws, float* __restrict__ out, int B) {
    int b = blockIdx.x * blockDim.x + threadIdx.x;
    if (b >= B) return;
    const float* p = ws + (long)b * 8;
    float s1x = p[0], s1y = p[1], s1z = p[2], s2 = p[3];
    float pxs = p[4], pys = p[5], pzs = p[6], m = p[7];
    float inv = (m > 0.0f) ? (1.0f / m) : 1.0f;
    float vx = s1x - s2 * (pxs * inv);
    float vy = s1y - s2 * (pys * inv);
    float vz = s1z - s2 * (pzs * inv);
    out[b] = sqrtf(vx * vx + vy * vy + vz * vz);
}

extern "C" void kernel_launch(void* const* d_in, const int* in_sizes, int n_in,
                              void* d_out, int out_size, void* d_ws, size_t ws_size,
                              hipStream_t stream) {
    const float* x     = (const float*)d_in[0];
    const float* pos   = (const float*)d_in[1];
    const float* W1    = (const float*)d_in[2];
    const float* b1    = (const float*)d_in[3];
    const float* W2    = (const float*)d_in[4];
    const float* b2    = (const float*)d_in[5];
    const float* am    = (const float*)d_in[6];
    const int*   z     = (const int*)d_in[7];
    const int*   batch = (const int*)d_in[8];

    const int N   = in_sizes[7];
    const int amN = in_sizes[6] < 128 ? in_sizes[6] : 128;
    const int B   = out_size;
    float* ws  = (float*)d_ws;       // [B][8] accumulators
    float* out = (float*)d_out;

    const int nChunks = (N + 63) / 64;

    int zn = B * 8;
    hipLaunchKernelGGL(zero_ws_kernel, dim3((zn + 255) / 256), dim3(256), 0, stream, ws, zn);

    int grid = nChunks < MAIN_GRID ? nChunks : MAIN_GRID;
    hipLaunchKernelGGL(mlp_dipole_kernel, dim3(grid), dim3(256), 0, stream,
                       x, pos, W1, b1, W2, b2, am, z, batch, ws, N, nChunks, amN);

    hipLaunchKernelGGL(finalize_kernel, dim3((B + 255) / 256), dim3(256), 0, stream, ws, out, B);
}

// Round 7
// 120.318 us; speedup vs baseline: 1.0652x; 1.0652x over previous
//
#include <hip/hip_runtime.h>
#include <hip/hip_bf16.h>

typedef __bf16 v8bf16 __attribute__((ext_vector_type(8)));
typedef float  v4f32  __attribute__((ext_vector_type(4)));

#define MAIN_GRID 512

static __device__ __forceinline__ float silu_f(float v) {
    return v / (1.0f + __expf(-v));
}

static __device__ __forceinline__ v8bf16 cvt8(v4f32 f0, v4f32 f1) {
    v8bf16 t;
    t[0] = (__bf16)f0[0]; t[1] = (__bf16)f0[1]; t[2] = (__bf16)f0[2]; t[3] = (__bf16)f0[3];
    t[4] = (__bf16)f1[0]; t[5] = (__bf16)f1[1]; t[6] = (__bf16)f1[2]; t[7] = (__bf16)f1[3];
    return t;
}

__global__ void zero_ws_kernel(float* __restrict__ ws, int n) {
    int i = blockIdx.x * blockDim.x + threadIdx.x;
    if (i < n) ws[i] = 0.0f;
}

// Load this wave's 16-row A-slice for chunk cc straight into VGPRs.
static __device__ __forceinline__ void stage_regs(
    const float* __restrict__ x, int N, long cc, int w, int l15, int lg,
    v4f32 (&st)[8])
{
    int arow = (int)(cc * 64) + w * 16 + l15;
    if (arow >= N) arow = N - 1;
    const float* xrow = x + (long)arow * 128 + lg * 8;
#pragma unroll
    for (int kt = 0; kt < 4; ++kt) {
        st[2 * kt]     = *reinterpret_cast<const v4f32*>(xrow + kt * 32);
        st[2 * kt + 1] = *reinterpret_cast<const v4f32*>(xrow + kt * 32 + 4);
    }
}

// Gather chunk cc's per-atom metadata (lanes 0..15 only).
static __device__ __forceinline__ void meta_regs(
    const float* __restrict__ pos, const int* __restrict__ batch,
    const int* __restrict__ z, int N, long cc, int w, int lane,
    float &gpx, float &gpy, float &gpz, int &gbi, int &gzi)
{
    if (lane < 16) {
        int a = (int)(cc * 64) + w * 16 + lane;
        int ac = (a < N) ? a : N - 1;
        gpx = pos[ac * 3 + 0]; gpy = pos[ac * 3 + 1]; gpz = pos[ac * 3 + 2];
        gbi = batch[ac]; gzi = z[ac];
    }
}

// One pipeline slot: consume st (staged 2 slots ago) -> MFMA -> restage st
// for chunk cnx (2 slots ahead) -> epilogue using meta staged 2 slots ago ->
// re-prefetch meta for cnx. Depth-2 distance means every waitcnt the
// compiler inserts only retires ops >= 2 full slots old (incl. atomics).
static __device__ __forceinline__ void process_slot(
    const float* __restrict__ x, const float* __restrict__ pos,
    const int* __restrict__ batch, const int* __restrict__ z,
    const float* amt, float* __restrict__ ws,
    const v8bf16 (&bf)[4][4], const float (&b1v)[4], const float (&w2v)[4],
    float b2s, int N, long nChunks,
    int w, int lane, int l15, int lg,
    v4f32 (&st)[8],
    float &gpx, float &gpy, float &gpz, int &gbi, int &gzi,
    long cc, long cnx)
{
    // 1. consume staged regs (issued 2 slots ago -> wait is a no-op)
    v8bf16 af[4];
#pragma unroll
    for (int kt = 0; kt < 4; ++kt)
        af[kt] = cvt8(st[2 * kt], st[2 * kt + 1]);

    // consume meta into locals before the regs get re-staged
    float px = gpx, py = gpy, pz = gpz;
    int   bi = gbi, zi = gzi;

    // 2. restage st for chunk cnx (2 slots ahead)
    if (cnx < nChunks) stage_regs(x, N, cnx, w, l15, lg, st);

    // 3. MFMA: acc[ct] += A(16x32) * W1(32x16) over 4 k-tiles
    v4f32 acc[4];
#pragma unroll
    for (int ct = 0; ct < 4; ++ct) acc[ct] = (v4f32){0.f, 0.f, 0.f, 0.f};
#pragma unroll
    for (int kt = 0; kt < 4; ++kt) {
#pragma unroll
        for (int ct = 0; ct < 4; ++ct)
            acc[ct] = __builtin_amdgcn_mfma_f32_16x16x32_bf16(af[kt], bf[kt][ct], acc[ct], 0, 0, 0);
    }

    // 4. re-prefetch meta for cnx (2 slots ahead)
    if (cnx < nChunks) meta_regs(pos, batch, z, N, cnx, w, lane, gpx, gpy, gpz, gbi, gzi);

    // 5. xo = silu(acc+b1).w2 reduced over the 64 channels
    float part0 = 0.f, part1 = 0.f, part2 = 0.f, part3 = 0.f;
#pragma unroll
    for (int ct = 0; ct < 4; ++ct) {
        part0 += silu_f(acc[ct][0] + b1v[ct]) * w2v[ct];
        part1 += silu_f(acc[ct][1] + b1v[ct]) * w2v[ct];
        part2 += silu_f(acc[ct][2] + b1v[ct]) * w2v[ct];
        part3 += silu_f(acc[ct][3] + b1v[ct]) * w2v[ct];
    }
#pragma unroll
    for (int d = 1; d < 16; d <<= 1) {
        part0 += __shfl_xor(part0, d);
        part1 += __shfl_xor(part1, d);
        part2 += __shfl_xor(part2, d);
        part3 += __shfl_xor(part3, d);
    }
    const int srcl = (l15 >> 2) << 4;
    float t0 = __shfl(part0, srcl);
    float t1 = __shfl(part1, srcl);
    float t2 = __shfl(part2, srcl);
    float t3 = __shfl(part3, srcl);
    const int rr = lane & 3;
    float xo = ((rr == 0) ? t0 : (rr == 1) ? t1 : (rr == 2) ? t2 : t3) + b2s;

    // 6. dipole accumulation for this wave's 16 atoms (regs + LDS only)
    if (lane < 16) {
        int a = (int)(cc * 64) + w * 16 + lane;
        bool valid = (a < N);
        float sc = valid ? 1.0f : 0.0f;
        float m  = amt[zi];
        float v0 = sc * xo * px, v1 = sc * xo * py, v2 = sc * xo * pz, v3 = sc * xo;
        float v4 = sc * m  * px, v5 = sc * m  * py, v6 = sc * m  * pz, v7 = sc * m;

        int bprev = __shfl_up(bi, 1);
        bool head = (lane == 0) || (bi != bprev);
        unsigned long long hm = __ballot(head);
        unsigned long long below = hm & ((2ull << lane) - 1ull);
        int rs = 63 - __builtin_clzll(below);

#define SCAN_STEP(d)                                                            \
        {                                                                       \
            float u0 = __shfl_up(v0, d), u1 = __shfl_up(v1, d);                 \
            float u2 = __shfl_up(v2, d), u3 = __shfl_up(v3, d);                 \
            float u4 = __shfl_up(v4, d), u5 = __shfl_up(v5, d);                 \
            float u6 = __shfl_up(v6, d), u7 = __shfl_up(v7, d);                 \
            if (lane >= rs + d) {                                               \
                v0 += u0; v1 += u1; v2 += u2; v3 += u3;                         \
                v4 += u4; v5 += u5; v6 += u6; v7 += u7;                         \
            }                                                                   \
        }
        SCAN_STEP(1)
        SCAN_STEP(2)
        SCAN_STEP(4)
        SCAN_STEP(8)
#undef SCAN_STEP

        bool tail = (lane == 15) || ((hm >> (lane + 1)) & 1ull);
        if (tail) {
            float* p = ws + (long)bi * 8;
            atomicAdd(p + 0, v0);
            atomicAdd(p + 1, v1);
            atomicAdd(p + 2, v2);
            atomicAdd(p + 3, v3);
            atomicAdd(p + 4, v4);
            atomicAdd(p + 5, v5);
            atomicAdd(p + 6, v6);
            atomicAdd(p + 7, v7);
        }
    }
}

__launch_bounds__(256)
__global__ void mlp_dipole_kernel(
    const float* __restrict__ x, const float* __restrict__ pos,
    const float* __restrict__ W1, const float* __restrict__ b1,
    const float* __restrict__ W2, const float* __restrict__ b2,
    const float* __restrict__ am, const int* __restrict__ z,
    const int* __restrict__ batch, float* __restrict__ ws,
    int N, int nChunks, int amN)
{
    __shared__ float amt[128];        // atomic-mass table (epilogue stays VMEM-free)

    const int tid  = threadIdx.x;
    const int lane = tid & 63;
    const int w    = tid >> 6;        // wave 0..3
    const int l15  = lane & 15;
    const int lg   = lane >> 4;

    if (tid < amN) amt[tid] = am[tid];

    float b1v[4], w2v[4];
#pragma unroll
    for (int ct = 0; ct < 4; ++ct) {
        b1v[ct] = b1[ct * 16 + l15];
        w2v[ct] = W2[ct * 16 + l15];
    }
    const float b2s = b2[0];

    // W1 fragments, register-resident for the whole kernel
    v8bf16 bf[4][4];
#pragma unroll
    for (int kt = 0; kt < 4; ++kt) {
#pragma unroll
        for (int ct = 0; ct < 4; ++ct) {
            const float* src = W1 + (ct * 16 + l15) * 128 + kt * 32 + lg * 8;
            v4f32 f0 = *reinterpret_cast<const v4f32*>(src);
            v4f32 f1 = *reinterpret_cast<const v4f32*>(src + 4);
            bf[kt][ct] = cvt8(f0, f1);
        }
    }

    __syncthreads();   // amt visible to all waves (only barrier in the kernel)

    const long gs = gridDim.x;
    long c = blockIdx.x;
    if (c >= nChunks) return;

    // ---- prologue: fill both pipeline slots ----
    v4f32 stA[8], stB[8];
#pragma unroll
    for (int i = 0; i < 8; ++i) { stA[i] = (v4f32){0.f,0.f,0.f,0.f}; stB[i] = (v4f32){0.f,0.f,0.f,0.f}; }
    float gApx = 0.f, gApy = 0.f, gApz = 0.f; int gAbi = 0, gAzi = 0;
    float gBpx = 0.f, gBpy = 0.f, gBpz = 0.f; int gBbi = 0, gBzi = 0;

    stage_regs(x, N, c, w, l15, lg, stA);
    meta_regs(pos, batch, z, N, c, w, lane, gApx, gApy, gApz, gAbi, gAzi);
    if (c + gs < nChunks) {
        stage_regs(x, N, c + gs, w, l15, lg, stB);
        meta_regs(pos, batch, z, N, c + gs, w, lane, gBpx, gBpy, gBpz, gBbi, gBzi);
    }

    // ---- main loop, hand-unrolled x2 (depth-2 ping-pong, static reg indexing) ----
    while (true) {
        process_slot(x, pos, batch, z, amt, ws, bf, b1v, w2v, b2s, N, nChunks,
                     w, lane, l15, lg, stA, gApx, gApy, gApz, gAbi, gAzi,
                     c, c + 2 * gs);
        c += gs;
        if (c >= nChunks) break;
        process_slot(x, pos, batch, z, amt, ws, bf, b1v, w2v, b2s, N, nChunks,
                     w, lane, l15, lg, stB, gBpx, gBpy, gBpz, gBbi, gBzi,
                     c, c + 2 * gs);
        c += gs;
        if (c >= nChunks) break;
    }
}

__global__ void finalize_kernel(const float* __restrict__ ws, float* __restrict__ out, int B) {
    int b = blockIdx.x * blockDim.x + threadIdx.x;
    if (b >= B) return;
    const float* p = ws + (long)b * 8;
    float s1x = p[0], s1y = p[1], s1z = p[2], s2 = p[3];
    float pxs = p[4], pys = p[5], pzs = p[6], m = p[7];
    float inv = (m > 0.0f) ? (1.0f / m) : 1.0f;
    float vx = s1x - s2 * (pxs * inv);
    float vy = s1y - s2 * (pys * inv);
    float vz = s1z - s2 * (pzs * inv);
    out[b] = sqrtf(vx * vx + vy * vy + vz * vz);
}

extern "C" void kernel_launch(void* const* d_in, const int* in_sizes, int n_in,
                              void* d_out, int out_size, void* d_ws, size_t ws_size,
                              hipStream_t stream) {
    const float* x     = (const float*)d_in[0];
    const float* pos   = (const float*)d_in[1];
    const float* W1    = (const float*)d_in[2];
    const float* b1    = (const float*)d_in[3];
    const float* W2    = (const float*)d_in[4];
    const float* b2    = (const float*)d_in[5];
    const float* am    = (const float*)d_in[6];
    const int*   z     = (const int*)d_in[7];
    const int*   batch = (const int*)d_in[8];

    const int N   = in_sizes[7];
    const int amN = in_sizes[6] < 128 ? in_sizes[6] : 128;
    const int B   = out_size;
    float* ws  = (float*)d_ws;       // [B][8] accumulators
    float* out = (float*)d_out;

    const int nChunks = (N + 63) / 64;

    int zn = B * 8;
    hipLaunchKernelGGL(zero_ws_kernel, dim3((zn + 255) / 256), dim3(256), 0, stream, ws, zn);

    int grid = nChunks < MAIN_GRID ? nChunks : MAIN_GRID;
    hipLaunchKernelGGL(mlp_dipole_kernel, dim3(grid), dim3(256), 0, stream,
                       x, pos, W1, b1, W2, b2, am, z, batch, ws, N, nChunks, amN);

    hipLaunchKernelGGL(finalize_kernel, dim3((B + 255) / 256), dim3(256), 0, stream, ws, out, B);
}